// Round 2
// baseline (476.543 us; speedup 1.0000x reference)
//
#include <hip/hip_runtime.h>
#include <stdint.h>

#define NN 8192
#define FF 256
#define HH 64

typedef __attribute__((ext_vector_type(8))) short bf16x8;
typedef __attribute__((ext_vector_type(4))) float f32x4;

__device__ __forceinline__ uint16_t f2bf(float f) {
  union { float f; uint32_t i; } c; c.f = f;
  uint32_t r = c.i + 0x7FFFu + ((c.i >> 16) & 1u);
  return (uint16_t)(r >> 16);
}

// ---------------------------------------------------------------------------
// K1 (r5..r11 verified GEMM core) + LDS-transpose tail emitting bf16 hT
// directly (verified last round: passed, absmax 0.015625). Unchanged.
// grid = 256 blocks x 32 rows.
// ---------------------------------------------------------------------------
__global__ __launch_bounds__(256) void k1_h(
    const float* __restrict__ x, const float* __restrict__ Wt,
    const float* __restrict__ bt, uint16_t* __restrict__ hT) {
  __shared__ float wtT[256 * 65];
  __shared__ float sbt[64];
  __shared__ uint16_t s_tr[64][34];
  const int t = threadIdx.x;
  const int lane = t & 63;
  const int w = t >> 6;

  for (int i = 0; i < 64; ++i)
    wtT[t * 65 + i] = Wt[(size_t)i * FF + t];
  if (t < 64) sbt[t] = bt[t];
  __syncthreads();

  const int n0 = blockIdx.x * 32;
  const int r0 = n0 + w * 8;
  const float binit = sbt[lane];
  float acc[8];
#pragma unroll
  for (int r = 0; r < 8; ++r) acc[r] = binit;

  for (int f4 = 0; f4 < FF; f4 += 4) {
    float4 xs[8];
#pragma unroll
    for (int r = 0; r < 8; ++r)
      xs[r] = *(const float4*)(x + (size_t)(r0 + r) * FF + f4);
    const float wt0 = wtT[(f4 + 0) * 65 + lane];
    const float wt1 = wtT[(f4 + 1) * 65 + lane];
    const float wt2 = wtT[(f4 + 2) * 65 + lane];
    const float wt3 = wtT[(f4 + 3) * 65 + lane];
#pragma unroll
    for (int r = 0; r < 8; ++r)
      acc[r] += xs[r].x * wt0 + xs[r].y * wt1 + xs[r].z * wt2 + xs[r].w * wt3;
  }

#pragma unroll
  for (int r = 0; r < 8; ++r)
    s_tr[lane][w * 8 + r] = f2bf(acc[r]);
  __syncthreads();
#pragma unroll
  for (int i = 0; i < 4; ++i) {
    int idx = i * 256 + t;
    int c = idx >> 4;
    int d = idx & 15;
    uint32_t v = (uint32_t)s_tr[c][2 * d] | ((uint32_t)s_tr[c][2 * d + 1] << 16);
    *(uint32_t*)(hT + (size_t)c * NN + n0 + 2 * d) = v;
  }
}

// ---------------------------------------------------------------------------
// K2F: fused attention-aggregate + epilogue. grid = 512 (16 rows/block),
// block = 256 (4 waves). NEW structure:
//  * adj staged through LDS in 1024-col tiles: staging instr i reads 4 KB
//    CONTIGUOUS from one adj row (DRAM-friendly), packs to bf16 via the
//    verified (lo|hi<<16)*0x3F80 trick, stores XOR-swizzled (^(row&7)<<4).
//  * MFMA core: verbatim r8/r11 fragment/accumulator maps; A-frags now come
//    from LDS (ds_read_b128, swizzle-matched, conflict-free); B-frags (hT)
//    unchanged global loads (hT is 1 MB, L2-resident).
//  * deg computed exactly by MFMA with an all-ones B operand (f32 integer
//    sums, exact) -> no per-lane popcount path at all.
//  * k3 epilogue (r4/r8-verified maps) fused verbatim; s_nb/s_y alias the
//    dead adj tile. No nb_part buffers, no split-K.
// ---------------------------------------------------------------------------
__global__ __launch_bounds__(256) void k2f(
    const int* __restrict__ adj, const uint16_t* __restrict__ hT,
    const float* __restrict__ x, const float* __restrict__ Wp,
    const float* __restrict__ bp, const float* __restrict__ gamma,
    const float* __restrict__ beta, float* __restrict__ out) {
  // layout: [0,32K) af tile (epilogue aliases: s_nb 4K @0, s_y 16K @4096)
  //         [32K,48K) s_part   [48K, +256) s_degw
  __shared__ __align__(16) unsigned char smem[49408];
  unsigned char* af = smem;
  float (*s_part)[16][64] = (float (*)[16][64])(smem + 32768);
  float (*s_degw)[16]     = (float (*)[16])(smem + 32768 + 16384);
  float (*s_nb)[64]       = (float (*)[64])(smem);
  float* s_y              = (float*)(smem + 4096);

  const int t    = threadIdx.x;
  const int w    = t >> 6;
  const int lane = t & 63;
  const int m    = lane & 15;
  const int q    = lane >> 4;
  const int row0 = blockIdx.x * 16;

  bf16x8 vone;
#pragma unroll
  for (int j = 0; j < 8; ++j) vone[j] = (short)0x3F80;

  f32x4 acc0 = 0, acc1 = 0, acc2 = 0, acc3 = 0, accd = 0;
  const uint16_t* __restrict__ hrow = hT + (size_t)m * NN;
  const int rsw = (m & 7) << 4;          // read-side swizzle

  for (int tile = 0; tile < 8; ++tile) {
    const int c0 = tile * 1024;
    // ---- stage: instr i = 4KB contiguous read of adj row (row0+i) ----
#pragma unroll
    for (int i = 0; i < 16; ++i) {
      int4 a = *(const int4*)(adj + (size_t)(row0 + i) * NN + c0 + t * 4);
      uint32_t lo = ((uint32_t)a.x | ((uint32_t)a.y << 16)) * 0x3F80u;
      uint32_t hi = ((uint32_t)a.z | ((uint32_t)a.w << 16)) * 0x3F80u;
      uint2 w2; w2.x = lo; w2.y = hi;
      uint32_t boff = (uint32_t)(t * 8) ^ (uint32_t)((i & 7) << 4);
      *(uint2*)(af + (i << 11) + boff) = w2;
    }
    __syncthreads();
    // ---- compute: wave w owns local cols [w*256, w*256+256) ----
#pragma unroll
    for (int it = 0; it < 4; ++it) {
      const int kl = w * 256 + it * 64;       // local col in tile
      const int k0 = c0 + kl + q * 8;         // global col, chunk A
      const int k1 = k0 + 32;                 // chunk B
      // A-frags from swizzled LDS
      bf16x8 afA = *(const bf16x8*)(af + (m << 11) +
                                    ((uint32_t)((kl + q * 8) * 2) ^ rsw));
      bf16x8 afB = *(const bf16x8*)(af + (m << 11) +
                                    ((uint32_t)((kl + q * 8 + 32) * 2) ^ rsw));
      // B-frags (hT), verbatim r11 pattern
      bf16x8 b0 = *(const bf16x8*)(hrow + k0);
      bf16x8 b1 = *(const bf16x8*)(hrow + 16 * NN + k0);
      bf16x8 b2 = *(const bf16x8*)(hrow + 32 * NN + k0);
      bf16x8 b3 = *(const bf16x8*)(hrow + 48 * NN + k0);
      bf16x8 d0 = *(const bf16x8*)(hrow + k1);
      bf16x8 d1 = *(const bf16x8*)(hrow + 16 * NN + k1);
      bf16x8 d2 = *(const bf16x8*)(hrow + 32 * NN + k1);
      bf16x8 d3 = *(const bf16x8*)(hrow + 48 * NN + k1);
      acc0 = __builtin_amdgcn_mfma_f32_16x16x32_bf16(afA, b0, acc0, 0, 0, 0);
      acc1 = __builtin_amdgcn_mfma_f32_16x16x32_bf16(afA, b1, acc1, 0, 0, 0);
      acc2 = __builtin_amdgcn_mfma_f32_16x16x32_bf16(afA, b2, acc2, 0, 0, 0);
      acc3 = __builtin_amdgcn_mfma_f32_16x16x32_bf16(afA, b3, acc3, 0, 0, 0);
      accd = __builtin_amdgcn_mfma_f32_16x16x32_bf16(afA, vone, accd, 0, 0, 0);
      acc0 = __builtin_amdgcn_mfma_f32_16x16x32_bf16(afB, d0, acc0, 0, 0, 0);
      acc1 = __builtin_amdgcn_mfma_f32_16x16x32_bf16(afB, d1, acc1, 0, 0, 0);
      acc2 = __builtin_amdgcn_mfma_f32_16x16x32_bf16(afB, d2, acc2, 0, 0, 0);
      acc3 = __builtin_amdgcn_mfma_f32_16x16x32_bf16(afB, d3, acc3, 0, 0, 0);
      accd = __builtin_amdgcn_mfma_f32_16x16x32_bf16(afB, vone, accd, 0, 0, 0);
    }
    __syncthreads();
  }

  // ---- acc -> s_part (r8 verbatim map) + deg from MFMA ----
#pragma unroll
  for (int rg = 0; rg < 4; ++rg) {
    (*s_part)[0][0] = (*s_part)[0][0];  // no-op to keep pointer form obvious
  }
#pragma unroll
  for (int rg = 0; rg < 4; ++rg) {
    s_part[w][q * 4 + rg][ 0 + m] = acc0[rg];
    s_part[w][q * 4 + rg][16 + m] = acc1[rg];
    s_part[w][q * 4 + rg][32 + m] = acc2[rg];
    s_part[w][q * 4 + rg][48 + m] = acc3[rg];
  }
  if (m == 0) {
#pragma unroll
    for (int rg = 0; rg < 4; ++rg) s_degw[w][q * 4 + rg] = accd[rg];
  }
  __syncthreads();

  // ---- cross-wave reduce -> s_nb (aliases dead af region) ----
  for (int idx = t; idx < 16 * 64; idx += 256) {
    int r = idx >> 6, c = idx & 63;
    float s = s_part[0][r][c] + s_part[1][r][c] +
              s_part[2][r][c] + s_part[3][r][c];
    float d = s_degw[0][r] + s_degw[1][r] + s_degw[2][r] + s_degw[3][r];
    s_nb[r][c] = (d > 0.5f) ? s / d : 0.f;
  }
  __syncthreads();

  // ---- tf = nb @ Wp^T + bp ; y = x + tf  (r4-verified, verbatim) ----
  {
    const int f = t;
    float wp[64];
    const float* wrow = Wp + (size_t)f * HH;
#pragma unroll
    for (int j = 0; j < 16; ++j) {
      float4 v = *(const float4*)(wrow + j * 4);
      wp[j * 4 + 0] = v.x; wp[j * 4 + 1] = v.y;
      wp[j * 4 + 2] = v.z; wp[j * 4 + 3] = v.w;
    }
    const float bpf = bp[f];
    for (int r = 0; r < 16; ++r) {
      float a = bpf;
#pragma unroll
      for (int k = 0; k < 64; k += 4) {
        float4 nv = *(const float4*)&s_nb[r][k];
        a += nv.x * wp[k] + nv.y * wp[k + 1] + nv.z * wp[k + 2] + nv.w * wp[k + 3];
      }
      float y = x[(size_t)(row0 + r) * FF + f] + a;
      s_y[r * 256 + f] = y;
    }
  }
  __syncthreads();

  // ---- LayerNorm (r4-verified, verbatim) ----
  for (int i = 0; i < 4; ++i) {
    const int r = w * 4 + i;
    float4 v = *(const float4*)&s_y[r * 256 + lane * 4];
    float sum = v.x + v.y + v.z + v.w;
    float ss  = v.x * v.x + v.y * v.y + v.z * v.z + v.w * v.w;
#pragma unroll
    for (int o = 32; o >= 1; o >>= 1) {
      sum += __shfl_xor(sum, o, 64);
      ss  += __shfl_xor(ss, o, 64);
    }
    const float mu  = sum * (1.0f / 256.0f);
    const float var = ss * (1.0f / 256.0f) - mu * mu;
    const float rs  = rsqrtf(var + 1e-5f);
    const int f0 = lane * 4;
    float4 g = *(const float4*)(gamma + f0);
    float4 b = *(const float4*)(beta + f0);
    float4 o4;
    o4.x = g.x * (v.x - mu) * rs + b.x;
    o4.y = g.y * (v.y - mu) * rs + b.y;
    o4.z = g.z * (v.z - mu) * rs + b.z;
    o4.w = g.w * (v.w - mu) * rs + b.w;
    *(float4*)(out + (size_t)(row0 + r) * FF + f0) = o4;
  }
}

extern "C" void kernel_launch(void* const* d_in, const int* in_sizes, int n_in,
                              void* d_out, int out_size, void* d_ws, size_t ws_size,
                              hipStream_t stream) {
  const float* x     = (const float*)d_in[0];
  const int*   adj   = (const int*)d_in[1];
  const float* Wt    = (const float*)d_in[2];
  const float* bt    = (const float*)d_in[3];
  // d_in[4] = Wa, d_in[5] = ba: provably dead (softmax scores are row-constant)
  const float* Wp    = (const float*)d_in[6];
  const float* bp    = (const float*)d_in[7];
  const float* gamma = (const float*)d_in[8];
  const float* beta  = (const float*)d_in[9];
  float* out = (float*)d_out;

  // ws layout: hT 1 MB only
  uint16_t* hT = (uint16_t*)d_ws;

  k1_h<<<256, 256, 0, stream>>>(x, Wt, bt, hT);
  k2f <<<512, 256, 0, stream>>>(adj, hT, x, Wp, bp, gamma, beta, out);
}

// Round 6
// 436.693 us; speedup vs baseline: 1.0913x; 1.0913x over previous
//
#include <hip/hip_runtime.h>
#include <stdint.h>

#define NN 8192
#define FF 256
#define HH 64

typedef __attribute__((ext_vector_type(8))) short bf16x8;
typedef __attribute__((ext_vector_type(4))) float f32x4;

__device__ __forceinline__ uint16_t f2bf(float f) {
  union { float f; uint32_t i; } c; c.f = f;
  uint32_t r = c.i + 0x7FFFu + ((c.i >> 16) & 1u);
  return (uint16_t)(r >> 16);
}

// ---------------------------------------------------------------------------
// K1: verified r5..r11 GEMM core + verified LDS-transpose tail (passed R1/R2).
// Unchanged. grid = 256 x 32 rows.
// ---------------------------------------------------------------------------
__global__ __launch_bounds__(256) void k1_h(
    const float* __restrict__ x, const float* __restrict__ Wt,
    const float* __restrict__ bt, uint16_t* __restrict__ hT) {
  __shared__ float wtT[256 * 65];
  __shared__ float sbt[64];
  __shared__ uint16_t s_tr[64][34];
  const int t = threadIdx.x;
  const int lane = t & 63;
  const int w = t >> 6;

  for (int i = 0; i < 64; ++i)
    wtT[t * 65 + i] = Wt[(size_t)i * FF + t];
  if (t < 64) sbt[t] = bt[t];
  __syncthreads();

  const int n0 = blockIdx.x * 32;
  const int r0 = n0 + w * 8;
  const float binit = sbt[lane];
  float acc[8];
#pragma unroll
  for (int r = 0; r < 8; ++r) acc[r] = binit;

  for (int f4 = 0; f4 < FF; f4 += 4) {
    float4 xs[8];
#pragma unroll
    for (int r = 0; r < 8; ++r)
      xs[r] = *(const float4*)(x + (size_t)(r0 + r) * FF + f4);
    const float wt0 = wtT[(f4 + 0) * 65 + lane];
    const float wt1 = wtT[(f4 + 1) * 65 + lane];
    const float wt2 = wtT[(f4 + 2) * 65 + lane];
    const float wt3 = wtT[(f4 + 3) * 65 + lane];
#pragma unroll
    for (int r = 0; r < 8; ++r)
      acc[r] += xs[r].x * wt0 + xs[r].y * wt1 + xs[r].z * wt2 + xs[r].w * wt3;
  }

#pragma unroll
  for (int r = 0; r < 8; ++r)
    s_tr[lane][w * 8 + r] = f2bf(acc[r]);
  __syncthreads();
#pragma unroll
  for (int i = 0; i < 4; ++i) {
    int idx = i * 256 + t;
    int c = idx >> 4;
    int d = idx & 15;
    uint32_t v = (uint32_t)s_tr[c][2 * d] | ((uint32_t)s_tr[c][2 * d + 1] << 16);
    *(uint32_t*)(hT + (size_t)c * NN + n0 + 2 * d) = v;
  }
}

// ---------------------------------------------------------------------------
// K2: VERIFIED R2 structure (block-wide barriered LDS staging, swizzled
// tile, deg-via-MFMA) with two parameter changes only:
//   * tile = 512 cols (16 KB) instead of 1024 -> LDS 33 KB -> 4 blocks/CU
//   * split-K 2 (grid 1024 = group x half) -> 4 blocks/CU resident; partials
//     go to disjoint nb_part/deg_part halves (R1-verified skeleton, passed).
// Barriers stay: stage -> sync -> compute -> sync per tile (the structure
// that passed R2). Wave-private barrier-free staging ABANDONED (3 fails).
// ---------------------------------------------------------------------------
__global__ __launch_bounds__(256) void k2_attn(
    const int* __restrict__ adj, const uint16_t* __restrict__ hT,
    float* __restrict__ nb_part, float* __restrict__ deg_part) {
  __shared__ __align__(16) unsigned char af[16 * 1024];  // 16 rows x 1 KB
  __shared__ float s_part[4][16][64];                    // 16 KB
  __shared__ float s_degw[4][16];

  const int t    = threadIdx.x;
  const int w    = t >> 6;
  const int lane = t & 63;
  const int m    = lane & 15;
  const int q    = lane >> 4;
  const int g    = blockIdx.x >> 1;
  const int half = blockIdx.x & 1;
  const int row0 = g * 16;
  const int rsw  = (m & 7) << 4;

  bf16x8 vone;
#pragma unroll
  for (int j = 0; j < 8; ++j) vone[j] = (short)0x3F80;

  f32x4 acc0 = 0, acc1 = 0, acc2 = 0, acc3 = 0, accd = 0;
  const uint16_t* __restrict__ hrow = hT + (size_t)m * NN;
  const int sr = t >> 7;      // 0/1: which row of the pair this thread stages
  const int sc = t & 127;     // int4 group within the 512-col row

  const int base = half * (NN / 2);
  for (int tile = 0; tile < 8; ++tile) {
    const int c0 = base + tile * 512;
    // ---- stage: instr i covers rows {2i, 2i+1}; 2 KB contiguous per row ----
#pragma unroll
    for (int i = 0; i < 8; ++i) {
      const int r_ = 2 * i + sr;
      int4 a = *(const int4*)(adj + (size_t)(row0 + r_) * NN + c0 + sc * 4);
      uint32_t lo = ((uint32_t)a.x | ((uint32_t)a.y << 16)) * 0x3F80u;
      uint32_t hi = ((uint32_t)a.z | ((uint32_t)a.w << 16)) * 0x3F80u;
      uint2 w2; w2.x = lo; w2.y = hi;
      *(uint2*)(af + r_ * 1024 + (((uint32_t)(sc * 8)) ^ ((r_ & 7) << 4))) = w2;
    }
    __syncthreads();
    // ---- compute: wave w owns cols [w*128, w*128+128) of the tile ----
#pragma unroll
    for (int it = 0; it < 2; ++it) {
      const int kl = w * 128 + it * 64;
      const int k0 = c0 + kl + q * 8;
      const int k1 = k0 + 32;
      bf16x8 afA = *(const bf16x8*)(af + m * 1024 +
                                    (((uint32_t)((kl + q * 8) * 2)) ^ rsw));
      bf16x8 afB = *(const bf16x8*)(af + m * 1024 +
                                    (((uint32_t)((kl + q * 8) * 2 + 64)) ^ rsw));
      bf16x8 b0 = *(const bf16x8*)(hrow + k0);
      bf16x8 b1 = *(const bf16x8*)(hrow + 16 * NN + k0);
      bf16x8 b2 = *(const bf16x8*)(hrow + 32 * NN + k0);
      bf16x8 b3 = *(const bf16x8*)(hrow + 48 * NN + k0);
      bf16x8 d0 = *(const bf16x8*)(hrow + k1);
      bf16x8 d1 = *(const bf16x8*)(hrow + 16 * NN + k1);
      bf16x8 d2 = *(const bf16x8*)(hrow + 32 * NN + k1);
      bf16x8 d3 = *(const bf16x8*)(hrow + 48 * NN + k1);
      acc0 = __builtin_amdgcn_mfma_f32_16x16x32_bf16(afA, b0, acc0, 0, 0, 0);
      acc1 = __builtin_amdgcn_mfma_f32_16x16x32_bf16(afA, b1, acc1, 0, 0, 0);
      acc2 = __builtin_amdgcn_mfma_f32_16x16x32_bf16(afA, b2, acc2, 0, 0, 0);
      acc3 = __builtin_amdgcn_mfma_f32_16x16x32_bf16(afA, b3, acc3, 0, 0, 0);
      accd = __builtin_amdgcn_mfma_f32_16x16x32_bf16(afA, vone, accd, 0, 0, 0);
      acc0 = __builtin_amdgcn_mfma_f32_16x16x32_bf16(afB, d0, acc0, 0, 0, 0);
      acc1 = __builtin_amdgcn_mfma_f32_16x16x32_bf16(afB, d1, acc1, 0, 0, 0);
      acc2 = __builtin_amdgcn_mfma_f32_16x16x32_bf16(afB, d2, acc2, 0, 0, 0);
      acc3 = __builtin_amdgcn_mfma_f32_16x16x32_bf16(afB, d3, acc3, 0, 0, 0);
      accd = __builtin_amdgcn_mfma_f32_16x16x32_bf16(afB, vone, accd, 0, 0, 0);
    }
    __syncthreads();
  }

  // ---- acc -> s_part (R2 verbatim map) + deg-via-MFMA (R2 verbatim) ----
#pragma unroll
  for (int rg = 0; rg < 4; ++rg) {
    s_part[w][q * 4 + rg][ 0 + m] = acc0[rg];
    s_part[w][q * 4 + rg][16 + m] = acc1[rg];
    s_part[w][q * 4 + rg][32 + m] = acc2[rg];
    s_part[w][q * 4 + rg][48 + m] = acc3[rg];
  }
  if (m == 0) {
#pragma unroll
    for (int rg = 0; rg < 4; ++rg) s_degw[w][q * 4 + rg] = accd[rg];
  }
  __syncthreads();

  // ---- cross-wave reduce -> this half's disjoint partial buffers ----
  float* __restrict__ dst = nb_part + ((size_t)half * NN + row0) * HH;
  for (int idx = t; idx < 16 * 64; idx += 256) {
    int r = idx >> 6, c = idx & 63;
    float s = s_part[0][r][c] + s_part[1][r][c] +
              s_part[2][r][c] + s_part[3][r][c];
    dst[(size_t)r * HH + c] = s;
  }
  if (t < 16) {
    float d = s_degw[0][t] + s_degw[1][t] + s_degw[2][t] + s_degw[3][t];
    deg_part[half * NN + row0 + t] = d;
  }
}

// ---------------------------------------------------------------------------
// K3: epilogue, R1-verified maps (passed). Only change: deg partials are
// float (from MFMA) instead of int.
// block = 256, 16 rows/block, grid = 512.
// ---------------------------------------------------------------------------
__global__ __launch_bounds__(256) void k3_epi(
    const float* __restrict__ x, const float* __restrict__ nb_part,
    const float* __restrict__ deg_part, const float* __restrict__ Wp,
    const float* __restrict__ bp, const float* __restrict__ gamma,
    const float* __restrict__ beta, float* __restrict__ out) {
  __shared__ float s_nb[16][64];
  __shared__ float s_y[16 * 256];

  const int t    = threadIdx.x;
  const int w    = t >> 6;
  const int lane = t & 63;
  const int row0 = blockIdx.x * 16;

  for (int idx = t; idx < 16 * 64; idx += 256) {
    int r = idx >> 6, c = idx & 63;
    float d = deg_part[row0 + r] + deg_part[NN + row0 + r];
    float s = nb_part[(size_t)(row0 + r) * HH + c] +
              nb_part[(size_t)(NN + row0 + r) * HH + c];
    s_nb[r][c] = (d > 0.5f) ? s / d : 0.f;
  }
  __syncthreads();

  // tf = neighbor @ Wp^T + bp ; y = x + tf   (r4-verified, verbatim)
  {
    const int f = t;
    float wp[64];
    const float* wrow = Wp + (size_t)f * HH;
#pragma unroll
    for (int j = 0; j < 16; ++j) {
      float4 v = *(const float4*)(wrow + j * 4);
      wp[j * 4 + 0] = v.x; wp[j * 4 + 1] = v.y;
      wp[j * 4 + 2] = v.z; wp[j * 4 + 3] = v.w;
    }
    const float bpf = bp[f];
    for (int r = 0; r < 16; ++r) {
      float a = bpf;
#pragma unroll
      for (int k = 0; k < 64; k += 4) {
        float4 nv = *(const float4*)&s_nb[r][k];
        a += nv.x * wp[k] + nv.y * wp[k + 1] + nv.z * wp[k + 2] + nv.w * wp[k + 3];
      }
      float y = x[(size_t)(row0 + r) * FF + f] + a;
      s_y[r * 256 + f] = y;
    }
  }
  __syncthreads();

  // LayerNorm (r4-verified, verbatim)
  for (int i = 0; i < 4; ++i) {
    const int r = w * 4 + i;
    float4 v = *(const float4*)&s_y[r * 256 + lane * 4];
    float sum = v.x + v.y + v.z + v.w;
    float ss  = v.x * v.x + v.y * v.y + v.z * v.z + v.w * v.w;
#pragma unroll
    for (int o = 32; o >= 1; o >>= 1) {
      sum += __shfl_xor(sum, o, 64);
      ss  += __shfl_xor(ss, o, 64);
    }
    const float mu  = sum * (1.0f / 256.0f);
    const float var = ss * (1.0f / 256.0f) - mu * mu;
    const float rs  = rsqrtf(var + 1e-5f);
    const int f0 = lane * 4;
    float4 g = *(const float4*)(gamma + f0);
    float4 b = *(const float4*)(beta + f0);
    float4 o4;
    o4.x = g.x * (v.x - mu) * rs + b.x;
    o4.y = g.y * (v.y - mu) * rs + b.y;
    o4.z = g.z * (v.z - mu) * rs + b.z;
    o4.w = g.w * (v.w - mu) * rs + b.w;
    *(float4*)(out + (size_t)(row0 + r) * FF + f0) = o4;
  }
}

extern "C" void kernel_launch(void* const* d_in, const int* in_sizes, int n_in,
                              void* d_out, int out_size, void* d_ws, size_t ws_size,
                              hipStream_t stream) {
  const float* x     = (const float*)d_in[0];
  const int*   adj   = (const int*)d_in[1];
  const float* Wt    = (const float*)d_in[2];
  const float* bt    = (const float*)d_in[3];
  // d_in[4] = Wa, d_in[5] = ba: provably dead (softmax scores are row-constant)
  const float* Wp    = (const float*)d_in[6];
  const float* bp    = (const float*)d_in[7];
  const float* gamma = (const float*)d_in[8];
  const float* beta  = (const float*)d_in[9];
  float* out = (float*)d_out;

  // ws layout: hT 1 MB | nb_part 4 MB (two halves) | deg_part 64 KB (float)
  uint16_t* hT       = (uint16_t*)d_ws;
  float*    nb_part  = (float*)((char*)d_ws + (1u << 20));
  float*    deg_part = (float*)((char*)d_ws + (5u << 20));

  k1_h   <<<256,  256, 0, stream>>>(x, Wt, bt, hT);
  k2_attn<<<1024, 256, 0, stream>>>(adj, hT, nb_part, deg_part);
  k3_epi <<<512,  256, 0, stream>>>(x, nb_part, deg_part, Wp, bp, gamma, beta, out);
}